// Round 16
// baseline (15.866 us; speedup 1.0000x reference)
//
#include <hip/hip_runtime.h>
#include <math.h>

#define BATCH 8
#define LEN   2048
#define FEAT  8
#define MROWS 64                      // 4 x 16-row A-frags, all waves
#define THREADS 1024                  // 16 waves, jo = w
#define JS    (LEN / 16)              // 128 targets per j-sixteenth
#define NCHUNK (JS / 16)              // 8 chunks x 4 MFMAs per wave
#define NBLK  (BATCH * (LEN / MROWS)) // 256 blocks = 1/CU
#define LOG2E 1.4426950408889634f
#define LN2   0.6931471805599453f
#define P2S   (2.0f * LOG2E)          // pred pre-scale

typedef _Float16 f16x8 __attribute__((ext_vector_type(8)));
typedef float    f32x4 __attribute__((ext_vector_type(4)));

__device__ __forceinline__ float exp2_hw(float x) {
    float d; asm("v_exp_f32 %0, %1" : "=v"(d) : "v"(x)); return d;
}
__device__ __forceinline__ float log2_hw(float x) {
    float d; asm("v_log_f32 %0, %1" : "=v"(d) : "v"(x)); return d;
}

// Round-16: halve j-loop LDS instructions AGAIN (the only mechanism with a
// verified cycle model: R10->R14 halved LDS instrs 1024->512/CU and dur fell
// by the predicted ~2.6us). Now 4 A-frags per wave: 16 waves each own a
// 128-target j-sixteenth; per chunk ONE ds_read_b128 + ONE b32 (broadcast)
// feed FOUR independent MFMAs (pred rows i0+col, +16, +32, +48) ->
// 256 LDS instr/CU in the j-loop. MFMA/exp2/per-pair VALU conserved.
// Math/layout: R14/R15-verified class -- MFMA data ONLY in lane-group 0
// (zeros elsewhere), S = 2*log2e*u.tau, x = S + mt2, row value =
// log2(sum_j exp2 x) - qp = log2(sum_j exp(-d~)), d~ = ||u-tau||^2 >= 0.
// qp applied exactly once per row post-reduction. Named frags/accs only
// (rule #20). Two-kernel structure (R5-7: atomic tails serialize ~6ns/RMW
// clustered at kernel end = dead end at this scale).
template <bool ATOMIC>
__global__ __launch_bounds__(THREADS, 4) void dtw_mfma(
    const float* __restrict__ pred, const float* __restrict__ target,
    float* __restrict__ partial_or_out)
{
    __shared__ f16x8 s_t16[LEN];         // 32 KB fp16 tau rows
    __shared__ float s_mt2[LEN];         // 8 KB  -log2e*||tau||^2
    __shared__ float s_red[MROWS * 16];  // 4 KB  per-(row, jo) partials
    __shared__ float s_qp[MROWS];        // 256 B per-row log2e*||u||^2

    const int tid = threadIdx.x;
    const int b   = blockIdx.x / (LEN / MROWS);
    const int rs  = blockIdx.x % (LEN / MROWS);
    const int jo  = tid >> 6;          // wave = j-sixteenth 0..15
    const int ln  = tid & 63;
    const int col = ln & 15;
    const int g   = ln >> 4;           // lane-group
    const int i0  = rs * MROWS;

    // ---- stage all 2048 target rows of batch b (2 rows per thread) ----
    const float4* t4 = (const float4*)(target + (size_t)b * LEN * FEAT);
    #pragma unroll
    for (int u = 0; u < LEN / THREADS; ++u) {
        const int jj = u * THREADS + tid;
        float4 ta = t4[(size_t)jj * 2];
        float4 tb = t4[(size_t)jj * 2 + 1];
        f16x8 h;
        h[0] = (_Float16)ta.x; h[1] = (_Float16)ta.y;
        h[2] = (_Float16)ta.z; h[3] = (_Float16)ta.w;
        h[4] = (_Float16)tb.x; h[5] = (_Float16)tb.y;
        h[6] = (_Float16)tb.z; h[7] = (_Float16)tb.w;
        float t2 = 0.f;
        #pragma unroll
        for (int e = 0; e < 8; ++e) { float f = (float)h[e]; t2 += f * f; }
        s_t16[jj] = h;
        s_mt2[jj] = -LOG2E * t2;
    }

    // ---- four A-frags: pred rows i0+col+16*f (all waves identical) ----
    f16x8 af0, af1, af2, af3;
    #pragma unroll
    for (int e = 0; e < 8; ++e) {
        af0[e] = (_Float16)0.f; af1[e] = (_Float16)0.f;
        af2[e] = (_Float16)0.f; af3[e] = (_Float16)0.f;
    }
    {
        const float* pb = pred + ((size_t)b * LEN + i0 + col) * FEAT;
        #pragma unroll
        for (int f = 0; f < 4; ++f) {
            const float4* pf4 = (const float4*)(pb + f * 16 * FEAT);
            float4 a = pf4[0], c = pf4[1];
            float pf[8] = {a.x, a.y, a.z, a.w, c.x, c.y, c.z, c.w};
            f16x8 r;
            float e2 = 0.f;
            #pragma unroll
            for (int e = 0; e < 8; ++e) {
                r[e] = (_Float16)(P2S * pf[e]);
                float x = (float)r[e];
                e2 += x * x;
            }
            if (g == 0) {
                if (f == 0) af0 = r;
                else if (f == 1) af1 = r;
                else if (f == 2) af2 = r;
                else af3 = r;
                if (jo == 0)
                    s_qp[f * 16 + col] = e2 * (0.25f / LOG2E); // log2e*||u||^2
            }
        }
    }

    __syncthreads();   // staging + s_qp visible

    // ---- j-loop: 8 chunks, 1 b128 + 1 b32 (broadcast) -> 4 MFMAs ----
    const int jbase = jo * JS;
    f32x4 ac0 = {0.f,0.f,0.f,0.f}, ac1 = {0.f,0.f,0.f,0.f};
    f32x4 ac2 = {0.f,0.f,0.f,0.f}, ac3 = {0.f,0.f,0.f,0.f};
    const f32x4 Z = {0.f, 0.f, 0.f, 0.f};
    #pragma unroll
    for (int ch = 0; ch < NCHUNK; ++ch) {
        const int j0 = jbase + ch * 16;
        f16x8 bfrag = s_t16[j0 + col];     // broadcast read
        float mt2c  = s_mt2[j0 + col];
        f32x4 S0 = __builtin_amdgcn_mfma_f32_16x16x32_f16(af0, bfrag, Z, 0,0,0);
        f32x4 S1 = __builtin_amdgcn_mfma_f32_16x16x32_f16(af1, bfrag, Z, 0,0,0);
        f32x4 S2 = __builtin_amdgcn_mfma_f32_16x16x32_f16(af2, bfrag, Z, 0,0,0);
        f32x4 S3 = __builtin_amdgcn_mfma_f32_16x16x32_f16(af3, bfrag, Z, 0,0,0);
        #pragma unroll
        for (int r = 0; r < 4; ++r) {
            ac0[r] += exp2_hw(S0[r] + mt2c);   // = 2^qp * exp(-d~)
            ac1[r] += exp2_hw(S1[r] + mt2c);
            ac2[r] += exp2_hw(S2[r] + mt2c);
            ac3[r] += exp2_hw(S3[r] + mt2c);
        }
    }

    // ---- sum each row across its 16-lane col group ----
    #pragma unroll
    for (int m = 1; m < 16; m <<= 1) {
        #pragma unroll
        for (int r = 0; r < 4; ++r) {
            ac0[r] += __shfl_xor(ac0[r], m);
            ac1[r] += __shfl_xor(ac1[r], m);
            ac2[r] += __shfl_xor(ac2[r], m);
            ac3[r] += __shfl_xor(ac3[r], m);
        }
    }
    if (col == 0) {
        #pragma unroll
        for (int r = 0; r < 4; ++r) {
            s_red[(g * 4 + r) * 16 + jo]      = ac0[r];
            s_red[(16 + g * 4 + r) * 16 + jo] = ac1[r];
            s_red[(32 + g * 4 + r) * 16 + jo] = ac2[r];
            s_red[(48 + g * 4 + r) * 16 + jo] = ac3[r];
        }
    }
    __syncthreads();

    // ---- per-row soft-min (subtract qp exactly), block total ----
    if (tid < MROWS) {
        float s = 0.f;
        #pragma unroll
        for (int q = 0; q < 16; ++q) s += s_red[tid * 16 + q];
        float v = log2_hw(s) - s_qp[tid];   // log2(sum_j exp(-d~))
        v += __shfl_xor(v, 1);
        v += __shfl_xor(v, 2);
        v += __shfl_xor(v, 4);
        v += __shfl_xor(v, 8);
        v += __shfl_xor(v, 16);
        v += __shfl_xor(v, 32);
        if (tid == 0) {
            float tot = -LN2 * v;           // -gamma * ln-sum over 64 rows
            if (ATOMIC) {
                atomicAdd(partial_or_out, tot * (1.0f / (BATCH * LEN)));
            } else {
                partial_or_out[blockIdx.x] = tot;
            }
        }
    }
}

__global__ __launch_bounds__(256) void dtw_reduce(
    const float* __restrict__ partial, float* __restrict__ out)
{
    __shared__ float s_w[4];
    const int tid = threadIdx.x;
    float v = partial[tid];               // NBLK = 256
    v += __shfl_xor(v, 1);
    v += __shfl_xor(v, 2);
    v += __shfl_xor(v, 4);
    v += __shfl_xor(v, 8);
    v += __shfl_xor(v, 16);
    v += __shfl_xor(v, 32);
    if ((tid & 63) == 0) s_w[tid >> 6] = v;
    __syncthreads();
    if (tid == 0)
        out[0] = (s_w[0] + s_w[1] + s_w[2] + s_w[3]) * (1.0f / (BATCH * LEN));
}

extern "C" void kernel_launch(void* const* d_in, const int* in_sizes, int n_in,
                              void* d_out, int out_size, void* d_ws, size_t ws_size,
                              hipStream_t stream) {
    const float* pred   = (const float*)d_in[0];
    const float* target = (const float*)d_in[1];
    float* out = (float*)d_out;

    if (ws_size >= NBLK * sizeof(float)) {
        float* partial = (float*)d_ws;
        dtw_mfma<false><<<NBLK, THREADS, 0, stream>>>(pred, target, partial);
        dtw_reduce<<<1, 256, 0, stream>>>(partial, out);
    } else {
        hipMemsetAsync(d_out, 0, sizeof(float), stream);
        dtw_mfma<true><<<NBLK, THREADS, 0, stream>>>(pred, target, out);
    }
}